// Round 11
// baseline (520.151 us; speedup 1.0000x reference)
//
#include <hip/hip_runtime.h>
#include <hip/hip_bf16.h>
#include <stdint.h>

#define N_NODES 100000
#define N_EDGES 300000
#define HID 256
#define NB_SCAN 98   // ceil(100000/1024)

typedef unsigned short u16;
typedef unsigned int u32;
typedef __attribute__((ext_vector_type(8))) short short8;
typedef __attribute__((ext_vector_type(4))) float f32x4;

__device__ __forceinline__ float bf2f(u16 u) {
    union { u32 i; float f; } c; c.i = ((u32)u) << 16; return c.f;
}
__device__ __forceinline__ u16 f2bf(float f) {
    union { float f; u32 i; } c; c.f = f;
    u32 x = c.i;
    u32 r = (x + 0x7fffu + ((x >> 16) & 1u)) >> 16;  // round-nearest-even
    return (u16)r;
}
__device__ __forceinline__ u32 pk2(float lo, float hi) {
    return (u32)f2bf(lo) | ((u32)f2bf(hi) << 16);
}
__device__ __forceinline__ void unpack8(uint4 u, float* f) {
    f[0] = bf2f(u.x & 0xffffu); f[1] = bf2f(u.x >> 16);
    f[2] = bf2f(u.y & 0xffffu); f[3] = bf2f(u.y >> 16);
    f[4] = bf2f(u.z & 0xffffu); f[5] = bf2f(u.z >> 16);
    f[6] = bf2f(u.w & 0xffffu); f[7] = bf2f(u.w >> 16);
}

// bijective XCD-chunked swizzle (m204)
__device__ __forceinline__ int xcd_map(int orig, int nwg) {
    int q = nwg >> 3, r = nwg & 7;
    int x = orig & 7, i = orig >> 3;
    return (x < r ? x * (q + 1) : r * (q + 1) + (x - r) * q) + i;
}

// ---------------- CSR build ----------------
__global__ void icnt_k(const int* __restrict__ dst, int* __restrict__ icnt) {
    int e = blockIdx.x * blockDim.x + threadIdx.x;
    if (e < N_EDGES) atomicAdd(&icnt[dst[e]], 1);
}

__global__ void scan1_k(const int* __restrict__ icnt, int* __restrict__ off,
                        int* __restrict__ bsum) {
    __shared__ int sh[256];
    int t = threadIdx.x;
    int base = blockIdx.x * 1024 + t * 4;
    int v[4];
    #pragma unroll
    for (int j = 0; j < 4; ++j) {
        int idx = base + j;
        v[j] = (idx < N_NODES) ? icnt[idx] : 0;
    }
    int s = v[0] + v[1] + v[2] + v[3];
    sh[t] = s;
    __syncthreads();
    #pragma unroll
    for (int d = 1; d < 256; d <<= 1) {
        int x = (t >= d) ? sh[t - d] : 0;
        __syncthreads();
        if (t >= d) sh[t] += x;
        __syncthreads();
    }
    int excl = sh[t] - s;
    #pragma unroll
    for (int j = 0; j < 4; ++j) {
        int idx = base + j;
        if (idx < N_NODES) off[idx] = excl;
        excl += v[j];
    }
    if (t == 255) bsum[blockIdx.x] = sh[255];
}

__global__ void scan2_k(int* __restrict__ bsum) {
    __shared__ int sh[128];
    int t = threadIdx.x;
    int v = (t < NB_SCAN) ? bsum[t] : 0;
    sh[t] = v;
    __syncthreads();
    #pragma unroll
    for (int d = 1; d < 128; d <<= 1) {
        int x = (t >= d) ? sh[t - d] : 0;
        __syncthreads();
        if (t >= d) sh[t] += x;
        __syncthreads();
    }
    if (t < NB_SCAN) bsum[t] = sh[t] - v;
}

__global__ void scan3_k(int* __restrict__ off, int* __restrict__ pos,
                        const int* __restrict__ bsum) {
    int idx = blockIdx.x * blockDim.x + threadIdx.x;
    if (idx < N_NODES) {
        int o = off[idx] + bsum[idx >> 10];
        off[idx] = o;
        pos[idx] = o;
    }
}

__global__ void scat_k(const int* __restrict__ src, const int* __restrict__ dst,
                       int* __restrict__ pos, int* __restrict__ csrc) {
    int e = blockIdx.x * blockDim.x + threadIdx.x;
    if (e < N_EDGES) {
        int slot = atomicAdd(&pos[dst[e]], 1);
        csrc[slot] = src[e];
    }
}

// ---------------- fused weight conversion ----------------
// out: BtIn[256][128] ++ Bt1[256][512] ++ Bt2[256][512] ++ Bt3[64][512]
__global__ void wtall_k(const float* __restrict__ W_in,
                        const float* __restrict__ Wl1, const float* __restrict__ Wr1,
                        const float* __restrict__ Wl2, const float* __restrict__ Wr2,
                        const float* __restrict__ Wl3, const float* __restrict__ Wr3,
                        u16* __restrict__ out) {
    int t = blockIdx.x * blockDim.x + threadIdx.x;
    if (t >= 327680) return;
    float v;
    if (t < 32768) {
        int n = t >> 7, k = t & 127;
        v = W_in[(size_t)k * 256 + n];
    } else if (t < 163840) {
        int t1 = t - 32768;
        int n = t1 >> 9, k = t1 & 511;
        v = (k < 256) ? Wl1[(size_t)k * 256 + n] : Wr1[(size_t)(k - 256) * 256 + n];
    } else if (t < 294912) {
        int t2 = t - 163840;
        int n = t2 >> 9, k = t2 & 511;
        v = (k < 256) ? Wl2[(size_t)k * 256 + n] : Wr2[(size_t)(k - 256) * 256 + n];
    } else {
        int t3 = t - 294912;
        int n = t3 >> 9, k = t3 & 511;
        v = (k < 256) ? Wl3[(size_t)k * 64 + n] : Wr3[(size_t)(k - 256) * 64 + n];
    }
    out[t] = f2bf(v);
}

// ---------------- MFMA GEMM with fused mean-gather A-staging ----------
// 1-D grid NPR*NCT (xcd_map chunking). 4 waves 2(M)x2(N); BK=64.
// AM 1: A1 fp32, reg-stage convert (input GEMM); no gather.
// AM 2: kc<SPLIT: A-tile = mean-gather from A2 via CSR (coff/cpos/csrc);
//       kc>=SPLIT: x-half via global_load_lds from A2.
// AM 3: like AM 2 but relu applied to gathered values AND x-half
//       (x-half reg-staged with relu). Source = pre-relu inp.
// MODE 0: v=acc+bias; outb=bf16(v).
// MODE 1: v=relu(acc+bias)+0.2*inp; outb=bf16(v).
// MODE 2: v=acc+bias; outf[row*64+col]=log_softmax(v) (BN=64 only).
template<int KC, int SPLIT, int MODE, int BM, int BN, int NCT, int AM>
__launch_bounds__(256, (BN >= 256) ? 2 : 4)
__global__ void mgemm_k(const u16* __restrict__ A1, const u16* __restrict__ A2,
                        int ldaB,
                        const u16* __restrict__ Bt,
                        const float* __restrict__ bias,
                        const u16* __restrict__ inp,
                        const int* __restrict__ coff,
                        const int* __restrict__ cpos,
                        const int* __restrict__ csrc,
                        u16* __restrict__ outb,
                        float* __restrict__ outf) {
    constexpr int HROWS = BM / 2;        // rows per M-half
    constexpr int MF  = HROWS / 16;      // 16-row frags per wave
    constexpr int WN  = BN / 2;          // cols per wave
    constexpr int NFC = WN / 16;         // 16-col frags per wave
    constexpr int ASZ = BM * 128;        // A tile bytes
    constexpr int BSZ = BN * 128;        // B tile bytes
    constexpr int EPL = HROWS * BN * 4;  // epilogue half-tile (f32)
    constexpr int LSZ = (ASZ + BSZ > EPL) ? (ASZ + BSZ) : EPL;
    constexpr int AI  = BM / 32;         // A issues per thread
    constexpr int BI  = BN / 32;         // B issues per thread
    __shared__ char lds[LSZ];

    const int tid  = threadIdx.x;
    const int lane = tid & 63;
    const int wid  = tid >> 6;           // 0..3
    const int wr   = wid >> 1;           // M half
    const int wc   = wid & 1;            // N half
    const int lg   = xcd_map(blockIdx.x, gridDim.x);
    const int r0   = (lg / NCT) * BM;
    const int c0   = (lg % NCT) * BN;

    f32x4 acc[MF][NFC];
    #pragma unroll
    for (int m = 0; m < MF; ++m)
        #pragma unroll
        for (int n = 0; n < NFC; ++n) acc[m][n] = (f32x4)(0.f);

    // swizzle: LDS[row][slot] = Data[row][slot ^ (row&7)]; row&7 == lane>>3
    const int sidx  = (lane & 7) ^ (lane >> 3);
    const int lrow  = lane >> 3;

    for (int kc = 0; kc < KC; ++kc) {
        // ---- stage A tile [BM x 128B] ----
        #pragma unroll
        for (int i = 0; i < AI; ++i) {
            const int rb = wid * (BM / 4) + i * 8;
            int rg = r0 + rb + lrow;
            rg = (rg < N_NODES) ? rg : (N_NODES - 1);
            char* dst = lds + (rb + lrow) * 128 + (lane & 7) * 16;
            if constexpr (AM == 1) {
                const char* g = (const char*)A1 + (size_t)rg * ldaB + kc * 256 + sidx * 32;
                float4 f0 = *(const float4*)g;
                float4 f1 = *(const float4*)(g + 16);
                uint4 w;
                w.x = pk2(f0.x, f0.y); w.y = pk2(f0.z, f0.w);
                w.z = pk2(f1.x, f1.y); w.w = pk2(f1.z, f1.w);
                *(uint4*)dst = w;
            } else if (kc < SPLIT) {
                // mean-gather: 8 lanes per row, lane covers swizzled 16B slot
                const int s = coff[rg], e = cpos[rg];
                const char* gbase = (const char*)A2 + kc * 128 + sidx * 16;
                float a[8] = {0.f, 0.f, 0.f, 0.f, 0.f, 0.f, 0.f, 0.f};
                for (int ii = s; ii < e; ++ii) {
                    int sr = csrc[ii];
                    uint4 u = *(const uint4*)(gbase + (size_t)sr * ldaB);
                    float f[8];
                    unpack8(u, f);
                    #pragma unroll
                    for (int j = 0; j < 8; ++j)
                        a[j] += (AM == 3) ? fmaxf(f[j], 0.f) : f[j];
                }
                const float inv = 1.0f / fmaxf((float)(e - s), 1.0f);
                uint4 w;
                w.x = pk2(a[0] * inv, a[1] * inv);
                w.y = pk2(a[2] * inv, a[3] * inv);
                w.z = pk2(a[4] * inv, a[5] * inv);
                w.w = pk2(a[6] * inv, a[7] * inv);
                *(uint4*)dst = w;
            } else if constexpr (AM == 3) {
                const char* g = (const char*)A2 + (size_t)rg * ldaB + (kc - SPLIT) * 128 + sidx * 16;
                uint4 u = *(const uint4*)g;
                float f[8];
                unpack8(u, f);
                uint4 w;
                w.x = pk2(fmaxf(f[0], 0.f), fmaxf(f[1], 0.f));
                w.y = pk2(fmaxf(f[2], 0.f), fmaxf(f[3], 0.f));
                w.z = pk2(fmaxf(f[4], 0.f), fmaxf(f[5], 0.f));
                w.w = pk2(fmaxf(f[6], 0.f), fmaxf(f[7], 0.f));
                *(uint4*)dst = w;
            } else {
                const char* g = (const char*)A2 + (size_t)rg * ldaB + (kc - SPLIT) * 128 + sidx * 16;
                __builtin_amdgcn_global_load_lds(
                    (__attribute__((address_space(1))) void*)g,
                    (__attribute__((address_space(3))) void*)(lds + rb * 128),
                    16, 0, 0);
            }
        }
        // ---- stage B tile [BN x 128B] ----
        #pragma unroll
        for (int i = 0; i < BI; ++i) {
            const int nb = wid * (BN / 4) + i * 8;
            const int nt = c0 + nb + lrow;
            const char* g = (const char*)Bt + (size_t)nt * (KC * 128) + kc * 128 + sidx * 16;
            __builtin_amdgcn_global_load_lds(
                (__attribute__((address_space(1))) void*)g,
                (__attribute__((address_space(3))) void*)(lds + ASZ + nb * 128),
                16, 0, 0);
        }
        __syncthreads();

        // ---- compute ----
        #pragma unroll
        for (int ks = 0; ks < 2; ++ks) {
            const int q = ((ks * 4 + (lane >> 4)) ^ (lane & 7)) << 4;
            short8 af[MF], bv[NFC];
            #pragma unroll
            for (int m = 0; m < MF; ++m)
                af[m] = *(const short8*)(lds + (wr * HROWS + m * 16 + (lane & 15)) * 128 + q);
            #pragma unroll
            for (int n = 0; n < NFC; ++n)
                bv[n] = *(const short8*)(lds + ASZ + (wc * WN + n * 16 + (lane & 15)) * 128 + q);
            #pragma unroll
            for (int m = 0; m < MF; ++m)
                #pragma unroll
                for (int n = 0; n < NFC; ++n)
                    acc[m][n] = __builtin_amdgcn_mfma_f32_16x16x32_bf16(
                        af[m], bv[n], acc[m][n], 0, 0, 0);
        }
        __syncthreads();
    }

    // ---- epilogue: two HROWS-row halves through LDS ----
    float* ep = (float*)lds;
    const int er = (lane >> 4) * 4;
    const int ec = lane & 15;
    constexpr int TPR = BN / 8;          // threads per row in pass 2
    constexpr int RPI = 256 / TPR;       // rows per iteration
    constexpr int NIT = HROWS / RPI;     // iterations per half
    const int rl0  = tid / TPR;
    const int colb = (tid % TPR) * 8;

    float bv8[8];
    #pragma unroll
    for (int j = 0; j < 8; ++j) bv8[j] = bias[c0 + colb + j];

    #pragma unroll
    for (int h = 0; h < 2; ++h) {
        if (wr == h) {
            #pragma unroll
            for (int m = 0; m < MF; ++m)
                #pragma unroll
                for (int n = 0; n < NFC; ++n) {
                    const int col = wc * WN + n * 16 + ec;
                    #pragma unroll
                    for (int r = 0; r < 4; ++r)
                        ep[(m * 16 + er + r) * BN + col] = acc[m][n][r];
                }
        }
        __syncthreads();
        #pragma unroll
        for (int rr = 0; rr < NIT; ++rr) {
            const int rl = rr * RPI + rl0;
            const int grow = r0 + h * HROWS + rl;
            f32x4 u0 = *(const f32x4*)(ep + rl * BN + colb);
            f32x4 u1 = *(const f32x4*)(ep + rl * BN + colb + 4);
            if (grow < N_NODES) {
                float v[8];
                #pragma unroll
                for (int j = 0; j < 4; ++j) { v[j] = u0[j] + bv8[j]; v[4 + j] = u1[j] + bv8[4 + j]; }
                const int gcol = c0 + colb;
                if constexpr (MODE == 0) {
                    uint4 q;
                    q.x = pk2(v[0], v[1]); q.y = pk2(v[2], v[3]);
                    q.z = pk2(v[4], v[5]); q.w = pk2(v[6], v[7]);
                    *(uint4*)(outb + (size_t)grow * HID + gcol) = q;
                } else if constexpr (MODE == 1) {
                    uint4 ip = *(const uint4*)(inp + (size_t)grow * HID + gcol);
                    float f[8];
                    unpack8(ip, f);
                    #pragma unroll
                    for (int j = 0; j < 8; ++j) v[j] = fmaxf(v[j], 0.f) + 0.2f * f[j];
                    uint4 q;
                    q.x = pk2(v[0], v[1]); q.y = pk2(v[2], v[3]);
                    q.z = pk2(v[4], v[5]); q.w = pk2(v[6], v[7]);
                    *(uint4*)(outb + (size_t)grow * HID + gcol) = q;
                } else {
                    float mx = v[0];
                    #pragma unroll
                    for (int j = 1; j < 8; ++j) mx = fmaxf(mx, v[j]);
                    #pragma unroll
                    for (int o2 = 1; o2 < 8; o2 <<= 1) mx = fmaxf(mx, __shfl_xor(mx, o2));
                    float se = 0.f;
                    #pragma unroll
                    for (int j = 0; j < 8; ++j) { v[j] -= mx; se += expf(v[j]); }
                    #pragma unroll
                    for (int o2 = 1; o2 < 8; o2 <<= 1) se += __shfl_xor(se, o2);
                    const float ls = logf(se);
                    *(float4*)(outf + (size_t)grow * 64 + gcol) =
                        make_float4(v[0] - ls, v[1] - ls, v[2] - ls, v[3] - ls);
                    *(float4*)(outf + (size_t)grow * 64 + gcol + 4) =
                        make_float4(v[4] - ls, v[5] - ls, v[6] - ls, v[7] - ls);
                }
            }
        }
        __syncthreads();
    }
}

extern "C" void kernel_launch(void* const* d_in, const int* in_sizes, int n_in,
                              void* d_out, int out_size, void* d_ws, size_t ws_size,
                              hipStream_t stream) {
    const float* x    = (const float*)d_in[0];
    const int*   ei   = (const int*)d_in[1];
    const float* W_in = (const float*)d_in[2];
    const float* b_in = (const float*)d_in[3];
    const float* Wl1  = (const float*)d_in[4];
    const float* bl1  = (const float*)d_in[5];
    const float* Wr1  = (const float*)d_in[6];
    const float* Wl2  = (const float*)d_in[7];
    const float* bl2  = (const float*)d_in[8];
    const float* Wr2  = (const float*)d_in[9];
    const float* Wl3  = (const float*)d_in[10];
    const float* bl3  = (const float*)d_in[11];
    const float* Wr3  = (const float*)d_in[12];
    float* out = (float*)d_out;

    const int* esrc = ei;
    const int* edst = ei + N_EDGES;

    char* ws = (char*)d_ws;
    u16* inp  = (u16*)(ws + 0);             // 51,200,000 (pre-relu H0)
    u16* x1   = (u16*)(ws + 51200000);      // 51,200,000 (layer-1 out)
    u16* x2   = (u16*)(ws + 102400000);     // 51,200,000 (layer-2 out)
    u16* BtIn = (u16*)(ws + 230400000);     // 65,536 (Bt buffers contiguous)
    u16* Bt1  = (u16*)(ws + 230465536);     // 262,144
    u16* Bt2  = (u16*)(ws + 230727680);     // 262,144
    u16* Bt3  = (u16*)(ws + 230989824);     // 65,536
    int* icnt = (int*)(ws + 231055360);     // 400,000
    int* coff = (int*)(ws + 231455360);     // 400,000
    int* cpos = (int*)(ws + 231855360);     // 400,000
    int* csrc = (int*)(ws + 232255360);     // 1,200,000
    int* bsum = (int*)(ws + 233455360);     // 512

    dim3 blk(256);
    dim3 gE((N_EDGES + 255) / 256);
    dim3 gN((N_NODES + 255) / 256);
    const int NPR128 = (N_NODES + 127) / 128;   // 782
    const int NPR64  = (N_NODES + 63) / 64;     // 1563
    dim3 gIn(NPR128 * 2);                       // input: BN=128, NCT=2
    dim3 gL12(NPR128);                          // combine: BN=256, NCT=1
    dim3 gL3(NPR64);                            // layer3: BM=64, BN=64

    // ---- CSR build ----
    hipMemsetAsync(icnt, 0, (size_t)N_NODES * 4, stream);
    icnt_k<<<gE, blk, 0, stream>>>(edst, icnt);
    scan1_k<<<NB_SCAN, blk, 0, stream>>>(icnt, coff, bsum);
    scan2_k<<<1, 128, 0, stream>>>(bsum);
    scan3_k<<<gN, blk, 0, stream>>>(coff, cpos, bsum);
    scat_k<<<gE, blk, 0, stream>>>(esrc, edst, cpos, csrc);

    // ---- weight conversions ----
    wtall_k<<<(327680 + 255) / 256, blk, 0, stream>>>(
        W_in, Wl1, Wr1, Wl2, Wr2, Wl3, Wr3, BtIn);

    // ---- input: inp = x @ W_in + b_in (pre-relu) ----
    mgemm_k<2, 2, 0, 128, 128, 2, 1><<<gIn, blk, 0, stream>>>(
        (const u16*)x, nullptr, 512, BtIn, b_in, nullptr,
        nullptr, nullptr, nullptr, inp, nullptr);

    // ---- layer 1: fused mean(relu(inp)) gather + GEMM + relu + 0.2*inp ----
    mgemm_k<8, 4, 1, 128, 256, 1, 3><<<gL12, blk, 0, stream>>>(
        nullptr, inp, 512, Bt1, bl1, inp,
        coff, cpos, csrc, x1, nullptr);

    // ---- layer 2: fused mean(x1) gather + GEMM + relu + 0.2*inp ----
    mgemm_k<8, 4, 1, 128, 256, 1, 2><<<gL12, blk, 0, stream>>>(
        nullptr, x1, 512, Bt2, bl2, inp,
        coff, cpos, csrc, x2, nullptr);

    // ---- layer 3: fused mean(x2) gather + GEMM + log_softmax ----
    mgemm_k<8, 4, 2, 64, 64, 1, 2><<<gL3, blk, 0, stream>>>(
        nullptr, x2, 512, Bt3, bl3, nullptr,
        coff, cpos, csrc, nullptr, out);
}

// Round 13
// 289.525 us; speedup vs baseline: 1.7966x; 1.7966x over previous
//
#include <hip/hip_runtime.h>
#include <hip/hip_bf16.h>
#include <stdint.h>

#define N_NODES 100000
#define N_EDGES 300000
#define HID 256
#define NB_SCAN 98   // ceil(100000/1024)

typedef unsigned short u16;
typedef unsigned int u32;
typedef __attribute__((ext_vector_type(8))) short short8;
typedef __attribute__((ext_vector_type(4))) float f32x4;

__device__ __forceinline__ float bf2f(u16 u) {
    union { u32 i; float f; } c; c.i = ((u32)u) << 16; return c.f;
}
__device__ __forceinline__ u16 f2bf(float f) {
    union { float f; u32 i; } c; c.f = f;
    u32 x = c.i;
    u32 r = (x + 0x7fffu + ((x >> 16) & 1u)) >> 16;  // round-nearest-even
    return (u16)r;
}
__device__ __forceinline__ u32 pk2(float lo, float hi) {
    return (u32)f2bf(lo) | ((u32)f2bf(hi) << 16);
}
__device__ __forceinline__ void unpack8(uint4 u, float* f) {
    f[0] = bf2f(u.x & 0xffffu); f[1] = bf2f(u.x >> 16);
    f[2] = bf2f(u.y & 0xffffu); f[3] = bf2f(u.y >> 16);
    f[4] = bf2f(u.z & 0xffffu); f[5] = bf2f(u.z >> 16);
    f[6] = bf2f(u.w & 0xffffu); f[7] = bf2f(u.w >> 16);
}

// bijective XCD-chunked swizzle (m204)
__device__ __forceinline__ int xcd_map(int orig, int nwg) {
    int q = nwg >> 3, r = nwg & 7;
    int x = orig & 7, i = orig >> 3;
    return (x < r ? x * (q + 1) : r * (q + 1) + (x - r) * q) + i;
}

// ---------------- CSR build ----------------
__global__ void icnt_k(const int* __restrict__ dst, int* __restrict__ icnt) {
    int e = blockIdx.x * blockDim.x + threadIdx.x;
    if (e < N_EDGES) atomicAdd(&icnt[dst[e]], 1);
}

__global__ void scan1_k(const int* __restrict__ icnt, int* __restrict__ off,
                        int* __restrict__ bsum) {
    __shared__ int sh[256];
    int t = threadIdx.x;
    int base = blockIdx.x * 1024 + t * 4;
    int v[4];
    #pragma unroll
    for (int j = 0; j < 4; ++j) {
        int idx = base + j;
        v[j] = (idx < N_NODES) ? icnt[idx] : 0;
    }
    int s = v[0] + v[1] + v[2] + v[3];
    sh[t] = s;
    __syncthreads();
    #pragma unroll
    for (int d = 1; d < 256; d <<= 1) {
        int x = (t >= d) ? sh[t - d] : 0;
        __syncthreads();
        if (t >= d) sh[t] += x;
        __syncthreads();
    }
    int excl = sh[t] - s;
    #pragma unroll
    for (int j = 0; j < 4; ++j) {
        int idx = base + j;
        if (idx < N_NODES) off[idx] = excl;
        excl += v[j];
    }
    if (t == 255) bsum[blockIdx.x] = sh[255];
}

__global__ void scan2_k(int* __restrict__ bsum) {
    __shared__ int sh[128];
    int t = threadIdx.x;
    int v = (t < NB_SCAN) ? bsum[t] : 0;
    sh[t] = v;
    __syncthreads();
    #pragma unroll
    for (int d = 1; d < 128; d <<= 1) {
        int x = (t >= d) ? sh[t - d] : 0;
        __syncthreads();
        if (t >= d) sh[t] += x;
        __syncthreads();
    }
    if (t < NB_SCAN) bsum[t] = sh[t] - v;
}

__global__ void scan3_k(int* __restrict__ off, int* __restrict__ pos,
                        const int* __restrict__ bsum) {
    int idx = blockIdx.x * blockDim.x + threadIdx.x;
    if (idx < N_NODES) {
        int o = off[idx] + bsum[idx >> 10];
        off[idx] = o;
        pos[idx] = o;
    }
}

__global__ void scat_k(const int* __restrict__ src, const int* __restrict__ dst,
                       int* __restrict__ pos, int* __restrict__ csrc) {
    int e = blockIdx.x * blockDim.x + threadIdx.x;
    if (e < N_EDGES) {
        int slot = atomicAdd(&pos[dst[e]], 1);
        csrc[slot] = src[e];
    }
}

// ---------------- CSR mean aggregation: 32 lanes/node, 2-edge ILP ----------
__global__ void aggc_k(const u16* __restrict__ x, const int* __restrict__ off,
                       const int* __restrict__ pos, const int* __restrict__ csrc,
                       u16* __restrict__ mean) {
    int node = blockIdx.x * (blockDim.x >> 5) + (threadIdx.x >> 5);
    if (node >= N_NODES) return;
    int lane = threadIdx.x & 31;
    const u16* xp = x + lane * 8;
    int s = off[node], e = pos[node];
    float acc[8] = {0.f, 0.f, 0.f, 0.f, 0.f, 0.f, 0.f, 0.f};
    int i = s;
    for (; i + 2 <= e; i += 2) {
        int sr0 = csrc[i];
        int sr1 = csrc[i + 1];
        uint4 u0 = *(const uint4*)(xp + (size_t)sr0 * HID);
        uint4 u1 = *(const uint4*)(xp + (size_t)sr1 * HID);
        float f0[8], f1[8];
        unpack8(u0, f0);
        unpack8(u1, f1);
        #pragma unroll
        for (int j = 0; j < 8; ++j) acc[j] += f0[j] + f1[j];
    }
    if (i < e) {
        int sr = csrc[i];
        uint4 u = *(const uint4*)(xp + (size_t)sr * HID);
        float f[8];
        unpack8(u, f);
        #pragma unroll
        for (int j = 0; j < 8; ++j) acc[j] += f[j];
    }
    float inv = 1.0f / fmaxf((float)(e - s), 1.0f);
    uint4 r;
    r.x = pk2(acc[0] * inv, acc[1] * inv);
    r.y = pk2(acc[2] * inv, acc[3] * inv);
    r.z = pk2(acc[4] * inv, acc[5] * inv);
    r.w = pk2(acc[6] * inv, acc[7] * inv);
    *(uint4*)(mean + (size_t)node * HID + lane * 8) = r;
}

// ---------------- fused weight conversion ----------------
// out: BtIn[256][128] ++ Bt1[256][512] ++ Bt2[256][512] ++ Bt3[64][512]
__global__ void wtall_k(const float* __restrict__ W_in,
                        const float* __restrict__ Wl1, const float* __restrict__ Wr1,
                        const float* __restrict__ Wl2, const float* __restrict__ Wr2,
                        const float* __restrict__ Wl3, const float* __restrict__ Wr3,
                        u16* __restrict__ out) {
    int t = blockIdx.x * blockDim.x + threadIdx.x;
    if (t >= 327680) return;
    float v;
    if (t < 32768) {
        int n = t >> 7, k = t & 127;
        v = W_in[(size_t)k * 256 + n];
    } else if (t < 163840) {
        int t1 = t - 32768;
        int n = t1 >> 9, k = t1 & 511;
        v = (k < 256) ? Wl1[(size_t)k * 256 + n] : Wr1[(size_t)(k - 256) * 256 + n];
    } else if (t < 294912) {
        int t2 = t - 163840;
        int n = t2 >> 9, k = t2 & 511;
        v = (k < 256) ? Wl2[(size_t)k * 256 + n] : Wr2[(size_t)(k - 256) * 256 + n];
    } else {
        int t3 = t - 294912;
        int n = t3 >> 9, k = t3 & 511;
        v = (k < 256) ? Wl3[(size_t)k * 64 + n] : Wr3[(size_t)(k - 256) * 64 + n];
    }
    out[t] = f2bf(v);
}

// ---------------- MFMA GEMM (BM x BN, XCD-chunked, 2-barrier sync loop) ----
// 1-D grid NPR*NCT; xcd_map makes NCT col-tiles of one A-panel adjacent.
// 4 waves 2(M)x2(N); BK=64.
// AM 0: A via global_load_lds (A1 for kc<SPLIT else A2), bf16.
// AM 1: A1 fp32, reg-stage convert (input GEMM).
// MODE 0: v=acc+bias; outb=bf16(v).
// MODE 1: v=relu(acc+bias)+0.2*inp; outb=bf16(v).
// MODE 2: v=acc+bias; outf[row*64+col]=log_softmax(v) (BN=64 only).
// MODE 3: v=acc+bias; outb2=bf16(v), outb=bf16(relu(v)).
template<int KC, int SPLIT, int MODE, int BM, int BN, int NCT, int AM>
__launch_bounds__(256, 4)
__global__ void mgemm_k(const u16* __restrict__ A1, const u16* __restrict__ A2,
                        int ldaB,
                        const u16* __restrict__ Bt,
                        const float* __restrict__ bias,
                        const u16* __restrict__ inp,
                        u16* __restrict__ outb, u16* __restrict__ outb2,
                        float* __restrict__ outf) {
    constexpr int HROWS = BM / 2;        // rows per M-half
    constexpr int MF  = HROWS / 16;      // 16-row frags per wave
    constexpr int WN  = BN / 2;          // cols per wave
    constexpr int NFC = WN / 16;         // 16-col frags per wave
    constexpr int ASZ = BM * 128;        // A tile bytes
    constexpr int BSZ = BN * 128;        // B tile bytes
    constexpr int EPL = HROWS * BN * 4;  // epilogue half-tile (f32)
    constexpr int LSZ0 = ASZ + BSZ;
    constexpr int LSZ = (LSZ0 > EPL) ? LSZ0 : EPL;
    constexpr int AI  = BM / 32;         // A issues per thread per step
    constexpr int BI  = BN / 32;         // B issues per thread per step
    __shared__ char lds[LSZ];

    const int tid  = threadIdx.x;
    const int lane = tid & 63;
    const int wid  = tid >> 6;           // 0..3
    const int wr   = wid >> 1;           // M half
    const int wc   = wid & 1;            // N half
    const int lg   = xcd_map(blockIdx.x, gridDim.x);
    const int r0   = (lg / NCT) * BM;
    const int c0   = (lg % NCT) * BN;

    f32x4 acc[MF][NFC];
    #pragma unroll
    for (int m = 0; m < MF; ++m)
        #pragma unroll
        for (int n = 0; n < NFC; ++n) acc[m][n] = (f32x4)(0.f);

    // swizzle: LDS[row][slot] = Data[row][slot ^ (row&7)]; row&7 == lane>>3
    const int sidx  = (lane & 7) ^ (lane >> 3);
    const int lrow  = lane >> 3;

    for (int kc = 0; kc < KC; ++kc) {
        // ---- stage A tile [BM x 128B] ----
        #pragma unroll
        for (int i = 0; i < AI; ++i) {
            const int rb = wid * (BM / 4) + i * 8;
            int rg = r0 + rb + lrow;
            rg = (rg < N_NODES) ? rg : (N_NODES - 1);
            if constexpr (AM == 1) {
                const char* g = (const char*)A1 + (size_t)rg * ldaB + kc * 256 + sidx * 32;
                float4 f0 = *(const float4*)g;
                float4 f1 = *(const float4*)(g + 16);
                uint4 w;
                w.x = pk2(f0.x, f0.y); w.y = pk2(f0.z, f0.w);
                w.z = pk2(f1.x, f1.y); w.w = pk2(f1.z, f1.w);
                *(uint4*)(lds + (rb + lrow) * 128 + (lane & 7) * 16) = w;
            } else {
                const u16* Ag = (kc < SPLIT) ? A1 : A2;
                const int  kb = ((kc < SPLIT) ? kc : kc - SPLIT) * 128;
                const char* g = (const char*)Ag + (size_t)rg * ldaB + kb + sidx * 16;
                __builtin_amdgcn_global_load_lds(
                    (__attribute__((address_space(1))) void*)g,
                    (__attribute__((address_space(3))) void*)(lds + rb * 128),
                    16, 0, 0);
            }
        }
        // ---- stage B tile [BN x 128B] ----
        #pragma unroll
        for (int i = 0; i < BI; ++i) {
            const int nb = wid * (BN / 4) + i * 8;
            const int nt = c0 + nb + lrow;
            const char* g = (const char*)Bt + (size_t)nt * (KC * 128) + kc * 128 + sidx * 16;
            __builtin_amdgcn_global_load_lds(
                (__attribute__((address_space(1))) void*)g,
                (__attribute__((address_space(3))) void*)(lds + ASZ + nb * 128),
                16, 0, 0);
        }
        __syncthreads();

        // ---- compute ----
        #pragma unroll
        for (int ks = 0; ks < 2; ++ks) {
            const int q = ((ks * 4 + (lane >> 4)) ^ (lane & 7)) << 4;
            short8 af[MF], bv[NFC];
            #pragma unroll
            for (int m = 0; m < MF; ++m)
                af[m] = *(const short8*)(lds + (wr * HROWS + m * 16 + (lane & 15)) * 128 + q);
            #pragma unroll
            for (int n = 0; n < NFC; ++n)
                bv[n] = *(const short8*)(lds + ASZ + (wc * WN + n * 16 + (lane & 15)) * 128 + q);
            #pragma unroll
            for (int m = 0; m < MF; ++m)
                #pragma unroll
                for (int n = 0; n < NFC; ++n)
                    acc[m][n] = __builtin_amdgcn_mfma_f32_16x16x32_bf16(
                        af[m], bv[n], acc[m][n], 0, 0, 0);
        }
        __syncthreads();
    }

    // ---- epilogue: two HROWS-row halves through LDS ----
    float* ep = (float*)lds;
    const int er = (lane >> 4) * 4;
    const int ec = lane & 15;
    constexpr int TPR = BN / 8;          // threads per row in pass 2
    constexpr int RPI = 256 / TPR;       // rows per iteration
    constexpr int NIT = HROWS / RPI;     // iterations per half
    const int rl0  = tid / TPR;
    const int colb = (tid % TPR) * 8;

    float bv8[8];
    #pragma unroll
    for (int j = 0; j < 8; ++j) bv8[j] = bias[c0 + colb + j];

    #pragma unroll
    for (int h = 0; h < 2; ++h) {
        if (wr == h) {
            #pragma unroll
            for (int m = 0; m < MF; ++m)
                #pragma unroll
                for (int n = 0; n < NFC; ++n) {
                    const int col = wc * WN + n * 16 + ec;
                    #pragma unroll
                    for (int r = 0; r < 4; ++r)
                        ep[(m * 16 + er + r) * BN + col] = acc[m][n][r];
                }
        }
        __syncthreads();
        #pragma unroll
        for (int rr = 0; rr < NIT; ++rr) {
            const int rl = rr * RPI + rl0;
            const int grow = r0 + h * HROWS + rl;
            f32x4 u0 = *(const f32x4*)(ep + rl * BN + colb);
            f32x4 u1 = *(const f32x4*)(ep + rl * BN + colb + 4);
            if (grow < N_NODES) {
                float v[8];
                #pragma unroll
                for (int j = 0; j < 4; ++j) { v[j] = u0[j] + bv8[j]; v[4 + j] = u1[j] + bv8[4 + j]; }
                const int gcol = c0 + colb;
                if constexpr (MODE == 0) {
                    uint4 q;
                    q.x = pk2(v[0], v[1]); q.y = pk2(v[2], v[3]);
                    q.z = pk2(v[4], v[5]); q.w = pk2(v[6], v[7]);
                    *(uint4*)(outb + (size_t)grow * HID + gcol) = q;
                } else if constexpr (MODE == 1) {
                    uint4 ip = *(const uint4*)(inp + (size_t)grow * HID + gcol);
                    float f[8];
                    unpack8(ip, f);
                    #pragma unroll
                    for (int j = 0; j < 8; ++j) v[j] = fmaxf(v[j], 0.f) + 0.2f * f[j];
                    uint4 q;
                    q.x = pk2(v[0], v[1]); q.y = pk2(v[2], v[3]);
                    q.z = pk2(v[4], v[5]); q.w = pk2(v[6], v[7]);
                    *(uint4*)(outb + (size_t)grow * HID + gcol) = q;
                } else if constexpr (MODE == 3) {
                    uint4 p, q;
                    p.x = pk2(v[0], v[1]); p.y = pk2(v[2], v[3]);
                    p.z = pk2(v[4], v[5]); p.w = pk2(v[6], v[7]);
                    q.x = pk2(fmaxf(v[0], 0.f), fmaxf(v[1], 0.f));
                    q.y = pk2(fmaxf(v[2], 0.f), fmaxf(v[3], 0.f));
                    q.z = pk2(fmaxf(v[4], 0.f), fmaxf(v[5], 0.f));
                    q.w = pk2(fmaxf(v[6], 0.f), fmaxf(v[7], 0.f));
                    *(uint4*)(outb2 + (size_t)grow * HID + gcol) = p;
                    *(uint4*)(outb + (size_t)grow * HID + gcol) = q;
                } else {
                    float mx = v[0];
                    #pragma unroll
                    for (int j = 1; j < 8; ++j) mx = fmaxf(mx, v[j]);
                    #pragma unroll
                    for (int o2 = 1; o2 < 8; o2 <<= 1) mx = fmaxf(mx, __shfl_xor(mx, o2));
                    float se = 0.f;
                    #pragma unroll
                    for (int j = 0; j < 8; ++j) { v[j] -= mx; se += expf(v[j]); }
                    #pragma unroll
                    for (int o2 = 1; o2 < 8; o2 <<= 1) se += __shfl_xor(se, o2);
                    const float ls = logf(se);
                    *(float4*)(outf + (size_t)grow * 64 + gcol) =
                        make_float4(v[0] - ls, v[1] - ls, v[2] - ls, v[3] - ls);
                    *(float4*)(outf + (size_t)grow * 64 + gcol + 4) =
                        make_float4(v[4] - ls, v[5] - ls, v[6] - ls, v[7] - ls);
                }
            }
        }
        __syncthreads();
    }
}

extern "C" void kernel_launch(void* const* d_in, const int* in_sizes, int n_in,
                              void* d_out, int out_size, void* d_ws, size_t ws_size,
                              hipStream_t stream) {
    const float* x    = (const float*)d_in[0];
    const int*   ei   = (const int*)d_in[1];
    const float* W_in = (const float*)d_in[2];
    const float* b_in = (const float*)d_in[3];
    const float* Wl1  = (const float*)d_in[4];
    const float* bl1  = (const float*)d_in[5];
    const float* Wr1  = (const float*)d_in[6];
    const float* Wl2  = (const float*)d_in[7];
    const float* bl2  = (const float*)d_in[8];
    const float* Wr2  = (const float*)d_in[9];
    const float* Wl3  = (const float*)d_in[10];
    const float* bl3  = (const float*)d_in[11];
    const float* Wr3  = (const float*)d_in[12];
    float* out = (float*)d_out;

    const int* esrc = ei;
    const int* edst = ei + N_EDGES;

    char* ws = (char*)d_ws;
    u16* inp  = (u16*)(ws + 0);             // 51,200,000 (pre-relu H0)
    u16* xA   = (u16*)(ws + 51200000);      // 51,200,000 (relu(H0); later L2 out)
    u16* x1   = (u16*)(ws + 102400000);     // 51,200,000 (layer-1 out)
    u16* mean = (u16*)(ws + 153600000);     // 51,200,000
    u16* BtIn = (u16*)(ws + 230400000);     // 65,536 (Bt buffers contiguous)
    u16* Bt1  = (u16*)(ws + 230465536);     // 262,144
    u16* Bt2  = (u16*)(ws + 230727680);     // 262,144
    u16* Bt3  = (u16*)(ws + 230989824);     // 65,536
    int* icnt = (int*)(ws + 231055360);     // 400,000
    int* coff = (int*)(ws + 231455360);     // 400,000
    int* cpos = (int*)(ws + 231855360);     // 400,000
    int* csrc = (int*)(ws + 232255360);     // 1,200,000
    int* bsum = (int*)(ws + 233455360);     // 512

    dim3 blk(256);
    dim3 gE((N_EDGES + 255) / 256);
    dim3 gN((N_NODES + 255) / 256);
    dim3 gAgg((N_NODES + 7) / 8);
    const int NPR128 = (N_NODES + 127) / 128;   // 782
    const int NPR64  = (N_NODES + 63) / 64;     // 1563
    dim3 gIn(NPR128 * 2);                       // input: BN=128, NCT=2
    dim3 gL12(NPR128 * 2);                      // combine: BN=128, NCT=2
    dim3 gL3(NPR64);                            // layer3: BM=64, BN=64

    // ---- CSR build ----
    hipMemsetAsync(icnt, 0, (size_t)N_NODES * 4, stream);
    icnt_k<<<gE, blk, 0, stream>>>(edst, icnt);
    scan1_k<<<NB_SCAN, blk, 0, stream>>>(icnt, coff, bsum);
    scan2_k<<<1, 128, 0, stream>>>(bsum);
    scan3_k<<<gN, blk, 0, stream>>>(coff, cpos, bsum);
    scat_k<<<gE, blk, 0, stream>>>(esrc, edst, cpos, csrc);

    // ---- weight conversions ----
    wtall_k<<<(327680 + 255) / 256, blk, 0, stream>>>(
        W_in, Wl1, Wr1, Wl2, Wr2, Wl3, Wr3, BtIn);

    // ---- input: inp = x @ W_in + b_in (pre-relu), xA = relu(inp) ----
    mgemm_k<2, 2, 3, 128, 128, 2, 1><<<gIn, blk, 0, stream>>>(
        (const u16*)x, nullptr, 512, BtIn, b_in, nullptr, xA, inp, nullptr);

    // ---- layer 1: mean = mean(xA); x1 = relu(mean@Wl1 + xA@Wr1 + b) + 0.2*inp
    aggc_k<<<gAgg, blk, 0, stream>>>(xA, coff, cpos, csrc, mean);
    mgemm_k<8, 4, 1, 128, 128, 2, 0><<<gL12, blk, 0, stream>>>(
        mean, xA, 512, Bt1, bl1, inp, x1, nullptr, nullptr);

    // ---- layer 2 (output into xA, dead after layer 1) ----
    aggc_k<<<gAgg, blk, 0, stream>>>(x1, coff, cpos, csrc, mean);
    mgemm_k<8, 4, 1, 128, 128, 2, 0><<<gL12, blk, 0, stream>>>(
        mean, x1, 512, Bt2, bl2, inp, xA, nullptr, nullptr);

    // ---- layer 3 (+ fused log_softmax) ----
    aggc_k<<<gAgg, blk, 0, stream>>>(xA, coff, cpos, csrc, mean);
    mgemm_k<8, 4, 2, 64, 64, 1, 0><<<gL3, blk, 0, stream>>>(
        mean, xA, 512, Bt3, bl3, nullptr, nullptr, nullptr, out);
}